// Round 15
// baseline (422.791 us; speedup 1.0000x reference)
//
#include <hip/hip_runtime.h>
#include <hip/hip_bf16.h>
#include <cstdint>
#include <cstddef>

typedef __attribute__((ext_vector_type(8))) short short8;   // 8 x bf16 (4 VGPRs)
typedef __attribute__((ext_vector_type(4))) float f32x4;    // MFMA accumulator
typedef __attribute__((ext_vector_type(4))) unsigned short ushort4v;

#define GLL(gp, lp) __builtin_amdgcn_global_load_lds(                         \
    (const __attribute__((address_space(1))) void*)(gp),                      \
    (__attribute__((address_space(3))) void*)(lp), 16, 0, 0)

static __device__ __forceinline__ unsigned short f2bf(float f) {
    union { float f; uint32_t u; } v; v.f = f;
    uint32_t r = v.u + 0x7FFF + ((v.u >> 16) & 1);   // round-to-nearest-even
    return (unsigned short)(r >> 16);
}
static __device__ __forceinline__ float bf2f(unsigned short u) {
    union { uint32_t u; float f; } v; v.u = (uint32_t)u << 16; return v.f;
}

// ---------------------------------------------------------------------------
// Fused preamble: weight transposes (KxN fp32 -> NxK bf16) + x fp32->bf16.
// ---------------------------------------------------------------------------
__global__ void pre_all_kernel(
    const float* __restrict__ x,
    const float* __restrict__ Wq, const float* __restrict__ Wk,
    const float* __restrict__ Wv, const float* __restrict__ Wo,
    const float* __restrict__ W1, const float* __restrict__ W2,
    unsigned short* __restrict__ xb,
    unsigned short* __restrict__ WqkvT, unsigned short* __restrict__ WoT,
    unsigned short* __restrict__ W1T, unsigned short* __restrict__ W2T)
{
    const int bid = blockIdx.x;
    const int tx = threadIdx.x, ty = threadIdx.y;      // block (32, 8)
    if (bid >= 12288) {                   // x conversion: 8 elems/thread
        const int tid = ty * 32 + tx;
        const size_t base = (size_t)(bid - 12288) * 2048 + tid * 8;
        float4 v0 = *reinterpret_cast<const float4*>(x + base);
        float4 v1 = *reinterpret_cast<const float4*>(x + base + 4);
        unsigned short* d = xb + base;
        d[0] = f2bf(v0.x); d[1] = f2bf(v0.y); d[2] = f2bf(v0.z); d[3] = f2bf(v0.w);
        d[4] = f2bf(v1.x); d[5] = f2bf(v1.y); d[6] = f2bf(v1.z); d[7] = f2bf(v1.w);
        return;
    }
    __shared__ float tile[32][33];
    const float* src; unsigned short* dst; int K, N, local;
    if (bid < 4096) {                     // Wq/Wk/Wv/Wo: 1024x1024
        int seg = bid >> 10; local = bid & 1023; K = 1024; N = 1024;
        src = (seg == 0) ? Wq : (seg == 1) ? Wk : (seg == 2) ? Wv : Wo;
        dst = (seg < 3) ? WqkvT + (size_t)seg * 1024 * 1024 : WoT;
    } else if (bid < 8192) {              // W1: 1024x4096
        local = bid - 4096; K = 1024; N = 4096; src = W1; dst = W1T;
    } else {                              // W2: 4096x1024
        local = bid - 8192; K = 4096; N = 1024; src = W2; dst = W2T;
    }
    const int ntx = N >> 5;
    const int n0 = (local % ntx) * 32, k0 = (local / ntx) * 32;
#pragma unroll
    for (int j = 0; j < 32; j += 8)
        tile[ty + j][tx] = src[(size_t)(k0 + ty + j) * N + n0 + tx];
    __syncthreads();
#pragma unroll
    for (int j = 0; j < 32; j += 8)
        dst[(size_t)(n0 + ty + j) * K + k0 + tx] = f2bf(tile[tx][ty + j]);
}

// ---------------------------------------------------------------------------
// 128x128 2-phase GEMM, A-IN-REGISTERS variant: A fragments are wave-private,
// so A bypasses LDS entirely (8x16B global->reg per lane per K-step, two
// named register sets a0/a1 for prefetch). Only B staged via global_load_lds
// (XOR-swizzled). LDS 32 KiB -> 3 blocks/CU (launch_bounds(256,3)).
// Per K-step: stageB(next)+loadA(next) issued FIRST, 32 MFMA on current,
// ONE vmcnt(0)+s_barrier. Split-K capable (grid.z, Kslice; ld = row stride).
// EPI: 0 = QKV split (+bias, Q*0.125*log2e, V transposed),
//      4 = bf16 partial to out0 + z*M*N
// ---------------------------------------------------------------------------
template <int EPI>
__global__ __launch_bounds__(256, 3) void gemm128_kernel(
    const unsigned short* __restrict__ A, const unsigned short* __restrict__ BT,
    int M, int N, int ld, int Kslice,
    const float* __restrict__ bias0, const float* __restrict__ bias1,
    const float* __restrict__ bias2,
    void* __restrict__ out0, void* __restrict__ out1, void* __restrict__ out2)
{
    __shared__ unsigned short Bsm[2][128 * 64];

    const int t = threadIdx.x;
    const int lane = t & 63, wv = t >> 6;
    const int wr = wv >> 1, wc = wv & 1;

    const int gx = gridDim.x;
    const int nwg = gx * gridDim.y;
    const int id = blockIdx.y * gx + blockIdx.x;
    const int swz = (id & 7) * (nwg >> 3) + (id >> 3);
    const int rowBase = (swz / gx) * 128;
    const int colBase = (swz % gx) * 128;
    const int koff = blockIdx.z * Kslice;

    const int r0 = t >> 3, c0 = t & 7;
    const int cg = c0 ^ (r0 & 7);
    const unsigned short* gB = BT + (size_t)(colBase + r0) * ld + koff + cg * 8;

    auto stageB = [&](int buf, int kt) {
#pragma unroll
        for (int j = 0; j < 4; j++)
            GLL(gB + (size_t)(32 * j) * ld + kt, &Bsm[buf][t * 8 + 2048 * j]);
    };

    // A direct-to-register base: row = rowBase + wr*64 + m*16 + (lane&15),
    // k-chunk = ks*32 + (lane>>4)*8
    const unsigned short* gAfrag =
        A + (size_t)(rowBase + wr * 64 + (lane & 15)) * ld + koff + ((lane >> 4) << 3);

    auto loadA = [&](short8 (&a)[4][2], int kt) {
#pragma unroll
        for (int m = 0; m < 4; m++)
#pragma unroll
            for (int ks = 0; ks < 2; ks++)
                a[m][ks] = *(const short8*)&gAfrag[(size_t)(m * 16) * ld + kt + ks * 32];
    };

    int boff[4][2];
#pragma unroll
    for (int n = 0; n < 4; n++)
#pragma unroll
        for (int ks = 0; ks < 2; ks++) {
            int cl = wc * 64 + n * 16 + (lane & 15);
            boff[n][ks] = cl * 64 + (((ks * 4 + (lane >> 4)) ^ (cl & 7)) << 3);
        }

    f32x4 acc[4][4];
#pragma unroll
    for (int m = 0; m < 4; m++)
#pragma unroll
        for (int n = 0; n < 4; n++) acc[m][n] = (f32x4){0.f, 0.f, 0.f, 0.f};

    auto compute = [&](short8 (&a)[4][2], int buf) {
        short8 b[4][2];
#pragma unroll
        for (int n = 0; n < 4; n++)
#pragma unroll
            for (int ks = 0; ks < 2; ks++)
                b[n][ks] = *(const short8*)&Bsm[buf][boff[n][ks]];
        __builtin_amdgcn_s_setprio(1);
#pragma unroll
        for (int m = 0; m < 4; m++)
#pragma unroll
            for (int n = 0; n < 4; n++) {
                acc[m][n] = __builtin_amdgcn_mfma_f32_16x16x32_bf16(
                    a[m][0], b[n][0], acc[m][n], 0, 0, 0);
                acc[m][n] = __builtin_amdgcn_mfma_f32_16x16x32_bf16(
                    a[m][1], b[n][1], acc[m][n], 0, 0, 0);
            }
        __builtin_amdgcn_s_setprio(0);
    };

    short8 a0[4][2], a1[4][2];
    stageB(0, 0);
    loadA(a0, 0);
    asm volatile("s_waitcnt vmcnt(0)" ::: "memory");
    __builtin_amdgcn_s_barrier();

    const int nt = Kslice >> 6;            // nt is even for all call sites
    for (int tt = 0; tt < nt; tt += 2) {
        const int kt1 = (tt + 1) << 6, kt2 = (tt + 2) << 6;
        // even step: compute a0/buf0, prefetch step tt+1 into a1/buf1
        if (tt + 1 < nt) { stageB(1, kt1); loadA(a1, kt1); }
        compute(a0, 0);
        asm volatile("s_waitcnt vmcnt(0)" ::: "memory");
        __builtin_amdgcn_sched_barrier(0);
        __builtin_amdgcn_s_barrier();
        if (tt + 1 < nt) {
            // odd step: compute a1/buf1, prefetch step tt+2 into a0/buf0
            if (tt + 2 < nt) { stageB(0, kt2); loadA(a0, kt2); }
            compute(a1, 1);
            asm volatile("s_waitcnt vmcnt(0)" ::: "memory");
            __builtin_amdgcn_sched_barrier(0);
            __builtin_amdgcn_s_barrier();
        }
    }

#pragma unroll
    for (int m = 0; m < 4; m++) {
#pragma unroll
        for (int n = 0; n < 4; n++) {
            const int col = colBase + wc * 64 + n * 16 + (lane & 15);
#pragma unroll
            for (int i = 0; i < 4; i++) {
                const int row = rowBase + wr * 64 + m * 16 + (lane >> 4) * 4 + i;
                float v = acc[m][n][i];
                if (EPI == 0) {
                    const int bb = row >> 11, s = row & 2047;
                    if (col < 1024) {
                        float q = (v + bias0[col]) * 0.18033688011112042f;
                        int h = col >> 6, d = col & 63;
                        ((unsigned short*)out0)[((size_t)(bb * 16 + h) * 2048 + s) * 64 + d] = f2bf(q);
                    } else if (col < 2048) {
                        int cc = col - 1024;
                        float kv = v + bias1[cc];
                        int h = cc >> 6, d = cc & 63;
                        ((unsigned short*)out1)[((size_t)(bb * 16 + h) * 2048 + s) * 64 + d] = f2bf(kv);
                    } else {
                        int cc = col - 2048;
                        float vv = v + bias2[cc];
                        int h = cc >> 6, d = cc & 63;
                        ((unsigned short*)out2)[((size_t)(bb * 16 + h) * 64 + d) * 2048 + s] = f2bf(vv);
                    }
                } else {   // EPI == 4: bf16 partial
                    ((unsigned short*)out0)[(size_t)blockIdx.z * M * N + (size_t)row * N + col]
                        = f2bf(v);
                }
            }
        }
    }
}

// ---------------------------------------------------------------------------
// 256x256 2-phase GEMM (R9-proven for FFN-up): BK=64, 512 thr = 8 waves.
// EPI: 2 = bf16 tanh-gelu(relu(+bias))
// ---------------------------------------------------------------------------
template <int EPI>
__global__ __launch_bounds__(512, 2) void gemm256_kernel(
    const unsigned short* __restrict__ A, const unsigned short* __restrict__ BT,
    int M, int N, int K,
    const float* __restrict__ bias0, void* __restrict__ out0)
{
    extern __shared__ unsigned short lds[];   // 65536 elems = 128 KiB

    const int t = threadIdx.x, lane = t & 63, w = t >> 6;
    const int wm = w >> 2, wn = w & 3;

    const int gx = gridDim.x;
    const int nwg = gx * gridDim.y;
    const int id = blockIdx.y * gx + blockIdx.x;
    const int swz = (id & 7) * (nwg >> 3) + (id >> 3);
    const int rowBase = (swz / gx) * 256;
    const int colBase = (swz % gx) * 256;

    const int r0 = t >> 3, c0 = t & 7;
    const int cg = c0 ^ (r0 & 7);
    const unsigned short* gA = A + (size_t)(rowBase + r0) * K + cg * 8;
    const unsigned short* gB = BT + (size_t)(colBase + r0) * K + cg * 8;

    auto stage = [&](int buf, int kt) {
#pragma unroll
        for (int j = 0; j < 4; j++) {
            GLL(gA + (size_t)(64 * j) * K + kt, &lds[buf * 16384 + t * 8 + 4096 * j]);
            GLL(gB + (size_t)(64 * j) * K + kt, &lds[32768 + buf * 16384 + t * 8 + 4096 * j]);
        }
    };

    int aoff[8][2], boff[4][2];
#pragma unroll
    for (int mf = 0; mf < 8; mf++)
#pragma unroll
        for (int ks = 0; ks < 2; ks++) {
            int rl = wm * 128 + mf * 16 + (lane & 15);
            aoff[mf][ks] = rl * 64 + (((ks * 4 + (lane >> 4)) ^ (rl & 7)) << 3);
        }
#pragma unroll
    for (int nf = 0; nf < 4; nf++)
#pragma unroll
        for (int ks = 0; ks < 2; ks++) {
            int cl = wn * 64 + nf * 16 + (lane & 15);
            boff[nf][ks] = cl * 64 + (((ks * 4 + (lane >> 4)) ^ (cl & 7)) << 3);
        }

    f32x4 acc[8][4];
#pragma unroll
    for (int mf = 0; mf < 8; mf++)
#pragma unroll
        for (int nf = 0; nf < 4; nf++) acc[mf][nf] = (f32x4){0.f, 0.f, 0.f, 0.f};

    stage(0, 0);
    asm volatile("s_waitcnt vmcnt(0)" ::: "memory");
    __builtin_amdgcn_s_barrier();

    const int nt = K >> 6;
    for (int tt = 0; tt < nt; ++tt) {
        const int cur = tt & 1;
        const int ab = cur * 16384, bbase = 32768 + cur * 16384;
        if (tt + 1 < nt) stage(cur ^ 1, (tt + 1) << 6);

        short8 b[4][2];
#pragma unroll
        for (int nf = 0; nf < 4; nf++)
#pragma unroll
            for (int ks = 0; ks < 2; ks++)
                b[nf][ks] = *(const short8*)&lds[bbase + boff[nf][ks]];
        __builtin_amdgcn_s_setprio(1);
#pragma unroll
        for (int mf = 0; mf < 8; mf++) {
            short8 a0 = *(const short8*)&lds[ab + aoff[mf][0]];
            short8 a1 = *(const short8*)&lds[ab + aoff[mf][1]];
#pragma unroll
            for (int nf = 0; nf < 4; nf++) {
                acc[mf][nf] = __builtin_amdgcn_mfma_f32_16x16x32_bf16(
                    a0, b[nf][0], acc[mf][nf], 0, 0, 0);
                acc[mf][nf] = __builtin_amdgcn_mfma_f32_16x16x32_bf16(
                    a1, b[nf][1], acc[mf][nf], 0, 0, 0);
            }
        }
        __builtin_amdgcn_s_setprio(0);

        asm volatile("s_waitcnt vmcnt(0)" ::: "memory");
        __builtin_amdgcn_sched_barrier(0);
        __builtin_amdgcn_s_barrier();
    }

#pragma unroll
    for (int mf = 0; mf < 8; mf++) {
#pragma unroll
        for (int nf = 0; nf < 4; nf++) {
            const int col = colBase + wn * 64 + nf * 16 + (lane & 15);
#pragma unroll
            for (int i = 0; i < 4; i++) {
                const int row = rowBase + wm * 128 + mf * 16 + (lane >> 4) * 4 + i;
                float z = acc[mf][nf][i] + bias0[col];
                if (z > 0.f) {
                    float u = 0.7978845608f * (z + 0.044715f * z * z * z);
                    float e = __builtin_amdgcn_exp2f(u * 2.8853900817779268f);
                    z = z * (1.f - 1.f / (e + 1.f));
                } else z = 0.f;
                ((unsigned short*)out0)[(size_t)row * N + col] = f2bf(z);
            }
        }
    }
}

// ---------------------------------------------------------------------------
// Flash attention (R14-proven): 512 threads = 8 waves x 16 q-rows.
// ---------------------------------------------------------------------------
__global__ __launch_bounds__(512) void flash_attn_kernel(
    const unsigned short* __restrict__ Qb, const unsigned short* __restrict__ Kb,
    const unsigned short* __restrict__ VT, unsigned short* __restrict__ ctxb)
{
    __shared__ unsigned short Ksm[2][64 * 64];
    __shared__ unsigned short Vsm[2][64 * 64];
    __shared__ unsigned short Psm[8][16 * 64];

    const int bh = blockIdx.y;
    const int q0 = blockIdx.x * 128;
    const int t = threadIdx.x, lane = t & 63, wv = t >> 6;

    const unsigned short* Qg = Qb + (size_t)bh * 2048 * 64;
    const unsigned short* Kg = Kb + (size_t)bh * 2048 * 64;
    const unsigned short* Vg = VT + (size_t)bh * 64 * 2048;

    short8 qf[2];
    {
        int r = q0 + wv * 16 + (lane & 15);
        qf[0] = *(const short8*)&Qg[(size_t)r * 64 + ((lane >> 4) << 3)];
        qf[1] = *(const short8*)&Qg[(size_t)r * 64 + 32 + ((lane >> 4) << 3)];
    }

    short8 onesf;
#pragma unroll
    for (int j = 0; j < 8; j++) onesf[j] = (short)0x3F80;   // bf16 1.0

    f32x4 o[4], lacc;
#pragma unroll
    for (int n = 0; n < 4; n++) o[n] = (f32x4){0.f, 0.f, 0.f, 0.f};
    lacc = (f32x4){0.f, 0.f, 0.f, 0.f};

    const int r0 = t >> 3, sl = t & 7;
    const int cg0 = sl ^ (r0 & 7);

    auto stageKV = [&](int buf, int kt) {
        GLL(&Kg[(size_t)(kt + r0) * 64 + cg0 * 8], &Ksm[buf][t * 8]);
        GLL(&Vg[(size_t)r0 * 2048 + kt + cg0 * 8], &Vsm[buf][t * 8]);
    };

    unsigned short* P = &Psm[wv][0];

    int pwaddr[4][4];
#pragma unroll
    for (int n = 0; n < 4; n++)
#pragma unroll
        for (int i = 0; i < 4; i++) {
            int rl = (lane >> 4) * 4 + i;
            int col = n * 16 + (lane & 15);
            pwaddr[n][i] = rl * 64 + ((((col >> 3) ^ (rl & 7)) << 3) | (col & 7));
        }

    stageKV(0, 0);
    asm volatile("s_waitcnt vmcnt(0)" ::: "memory");
    __builtin_amdgcn_s_barrier();

    for (int tt = 0; tt < 32; ++tt) {
        const int cur = tt & 1;
        if (tt + 1 < 32) stageKV(cur ^ 1, (tt + 1) << 6);   // prefetch FIRST

        f32x4 s[4];
        __builtin_amdgcn_s_setprio(1);
#pragma unroll
        for (int n = 0; n < 4; n++) {
            s[n] = (f32x4){0.f, 0.f, 0.f, 0.f};
            int rl = n * 16 + (lane & 15);
#pragma unroll
            for (int kb = 0; kb < 2; kb++) {
                int slot = ((kb << 2) + (lane >> 4)) ^ (rl & 7);
                short8 kf = *(const short8*)&Ksm[cur][rl * 64 + slot * 8];
                s[n] = __builtin_amdgcn_mfma_f32_16x16x32_bf16(qf[kb], kf, s[n], 0, 0, 0);
            }
        }
        __builtin_amdgcn_s_setprio(0);

#pragma unroll
        for (int n = 0; n < 4; n++)
#pragma unroll
            for (int i = 0; i < 4; i++) {
                float p = __builtin_amdgcn_exp2f(s[n][i]);
                union { float f; uint32_t u; } pv; pv.f = p;
                P[pwaddr[n][i]] = (unsigned short)(pv.u >> 16);
            }

        short8 pf[2];
        {
            int rl = lane & 15;
#pragma unroll
            for (int kb = 0; kb < 2; kb++) {
                int slot = ((kb << 2) + (lane >> 4)) ^ (rl & 7);
                pf[kb] = *(const short8*)&P[rl * 64 + slot * 8];
            }
        }
        __builtin_amdgcn_s_setprio(1);
        lacc = __builtin_amdgcn_mfma_f32_16x16x32_bf16(pf[0], onesf, lacc, 0, 0, 0);
        lacc = __builtin_amdgcn_mfma_f32_16x16x32_bf16(pf[1], onesf, lacc, 0, 0, 0);
#pragma unroll
        for (int n = 0; n < 4; n++) {
            int d = n * 16 + (lane & 15);
#pragma unroll
            for (int kb = 0; kb < 2; kb++) {
                int slot = ((kb << 2) + (lane >> 4)) ^ (d & 7);
                short8 vf = *(const short8*)&Vsm[cur][d * 64 + slot * 8];
                o[n] = __builtin_amdgcn_mfma_f32_16x16x32_bf16(pf[kb], vf, o[n], 0, 0, 0);
            }
        }
        __builtin_amdgcn_s_setprio(0);

        asm volatile("s_waitcnt vmcnt(0)" ::: "memory");
        __builtin_amdgcn_sched_barrier(0);
        __builtin_amdgcn_s_barrier();
    }

    const int bb = bh >> 4, h = bh & 15;
#pragma unroll
    for (int i = 0; i < 4; i++) {
        float linv = 1.f / lacc[i];
        int srow = q0 + wv * 16 + (lane >> 4) * 4 + i;
#pragma unroll
        for (int n = 0; n < 4; n++) {
            int d = n * 16 + (lane & 15);
            ctxb[((size_t)(bb * 2048 + srow)) * 1024 + h * 64 + d] =
                f2bf(o[n][i] * linv);
        }
    }
}

// ---------------------------------------------------------------------------
// LayerNorm over D=1024 with fused split-K reduce; bf16 partial inputs.
// ---------------------------------------------------------------------------
__global__ __launch_bounds__(256) void ln_kernel(
    const unsigned short* __restrict__ in0, const unsigned short* __restrict__ in1,
    const unsigned short* __restrict__ resid, const float* __restrict__ bias,
    const float* __restrict__ g, const float* __restrict__ bta,
    float* __restrict__ outf, unsigned short* __restrict__ outb)
{
    const int row = blockIdx.x;
    const int t = threadIdx.x, lane = t & 63, wv = t >> 6;
    const size_t base = (size_t)row * 1024 + t * 4;

    ushort4v u0 = *reinterpret_cast<const ushort4v*>(in0 + base);
    ushort4v u1 = *reinterpret_cast<const ushort4v*>(in1 + base);
    float4 xv;
    xv.x = bf2f(u0[0]) + bf2f(u1[0]);
    xv.y = bf2f(u0[1]) + bf2f(u1[1]);
    xv.z = bf2f(u0[2]) + bf2f(u1[2]);
    xv.w = bf2f(u0[3]) + bf2f(u1[3]);
    if (resid) {
        ushort4v ur = *reinterpret_cast<const ushort4v*>(resid + base);
        xv.x += bf2f(ur[0]); xv.y += bf2f(ur[1]);
        xv.z += bf2f(ur[2]); xv.w += bf2f(ur[3]);
    }
    {
        float4 bv = *reinterpret_cast<const float4*>(bias + t * 4);
        xv.x += bv.x; xv.y += bv.y; xv.z += bv.z; xv.w += bv.w;
    }

    float s = xv.x + xv.y + xv.z + xv.w;
    float ss = xv.x * xv.x + xv.y * xv.y + xv.z * xv.z + xv.w * xv.w;
#pragma unroll
    for (int off = 1; off < 64; off <<= 1) {
        s += __shfl_xor(s, off);
        ss += __shfl_xor(ss, off);
    }
    __shared__ float red[8];
    if (lane == 0) { red[wv] = s; red[4 + wv] = ss; }
    __syncthreads();
    s = red[0] + red[1] + red[2] + red[3];
    ss = red[4] + red[5] + red[6] + red[7];
    const float mu = s * (1.f / 1024.f);
    const float var = ss * (1.f / 1024.f) - mu * mu;
    const float inv = rsqrtf(var + 1e-12f);

    float4 gv = *reinterpret_cast<const float4*>(g + t * 4);
    float4 bv = *reinterpret_cast<const float4*>(bta + t * 4);
    float o0 = (xv.x - mu) * inv * gv.x + bv.x;
    float o1 = (xv.y - mu) * inv * gv.y + bv.y;
    float o2 = (xv.z - mu) * inv * gv.z + bv.z;
    float o3 = (xv.w - mu) * inv * gv.w + bv.w;

    if (outf)
        *reinterpret_cast<float4*>(outf + base) = (float4){o0, o1, o2, o3};
    if (outb) {
        unsigned short* ob = outb + base;
        ob[0] = f2bf(o0); ob[1] = f2bf(o1); ob[2] = f2bf(o2); ob[3] = f2bf(o3);
    }
}

// ---------------------------------------------------------------------------
extern "C" void kernel_launch(void* const* d_in, const int* in_sizes, int n_in,
                              void* d_out, int out_size, void* d_ws, size_t ws_size,
                              hipStream_t stream) {
    const float* x     = (const float*)d_in[0];
    const float* Wq    = (const float*)d_in[1];
    const float* bq    = (const float*)d_in[2];
    const float* Wk    = (const float*)d_in[3];
    const float* bk    = (const float*)d_in[4];
    const float* Wv    = (const float*)d_in[5];
    const float* bv    = (const float*)d_in[6];
    const float* Wo    = (const float*)d_in[7];
    const float* bo    = (const float*)d_in[8];
    const float* ln1_g = (const float*)d_in[9];
    const float* ln1_b = (const float*)d_in[10];
    const float* W1    = (const float*)d_in[11];
    const float* b1    = (const float*)d_in[12];
    const float* W2    = (const float*)d_in[13];
    const float* b2    = (const float*)d_in[14];
    const float* ln2_g = (const float*)d_in[15];
    const float* ln2_b = (const float*)d_in[16];
    float* out = (float*)d_out;

    const int B = 2, S = 2048, D = 1024, H = 16, F = 4096;
    const int M = B * S;                    // 4096 tokens

    char* w = (char*)d_ws;
    size_t off = 0;
    auto alloc = [&](size_t bytes) {
        size_t o = off; off += (bytes + 255) & ~(size_t)255; return o;
    };
    unsigned short* xb      = (unsigned short*)(w + alloc((size_t)M * D * 2));   // also ctxb
    unsigned short* WqkvT   = (unsigned short*)(w + alloc((size_t)3 * D * D * 2));
    unsigned short* WoT     = (unsigned short*)(w + alloc((size_t)D * D * 2));
    unsigned short* W1T     = (unsigned short*)(w + alloc((size_t)D * F * 2));
    unsigned short* W2T     = (unsigned short*)(w + alloc((size_t)F * D * 2));
    unsigned short* Qbuf    = (unsigned short*)(w + alloc((size_t)M * D * 2));
    unsigned short* Kbuf    = (unsigned short*)(w + alloc((size_t)M * D * 2));
    unsigned short* VTbuf   = (unsigned short*)(w + alloc((size_t)M * D * 2));
    unsigned short* z0      = (unsigned short*)(w + alloc((size_t)M * D * 2));   // bf16 partial 0
    unsigned short* z1      = (unsigned short*)(w + alloc((size_t)M * D * 2));   // bf16 partial 1
    unsigned short* attnlnb = (unsigned short*)(w + alloc((size_t)M * D * 2));   // LN1 out (bf16)
    unsigned short* hbuf    = (unsigned short*)(w + alloc((size_t)M * F * 2));
    unsigned short* ctxb    = xb;   // reuse (xb consumed by QKV GEMM before attn)

    hipFuncSetAttribute((const void*)gemm256_kernel<2>,
                        hipFuncAttributeMaxDynamicSharedMemorySize, 131072);

    // 1) fused preamble: weight transposes + x conversion (one launch)
    pre_all_kernel<<<14336, dim3(32, 8), 0, stream>>>(
        x, Wq, Wk, Wv, Wo, W1, W2, xb, WqkvT, WoT, W1T, W2T);

    // 2) fused QKV projection (128-tile 2-phase, A-in-registers)
    gemm128_kernel<0><<<dim3(3 * D / 128, M / 128, 1), 256, 0, stream>>>(
        xb, WqkvT, M, 3 * D, D, D, bq, bk, bv, Qbuf, Kbuf, VTbuf);

    // 3) flash attention -> ctx bf16 (token-major); 128 q-rows/block
    flash_attn_kernel<<<dim3(S / 128, B * H), 512, 0, stream>>>(
        Qbuf, Kbuf, VTbuf, ctxb);

    // 4) output projection, split-K=2 -> bf16 partials z0,z1
    gemm128_kernel<4><<<dim3(D / 128, M / 128, 2), 256, 0, stream>>>(
        ctxb, WoT, M, D, D, D / 2, nullptr, nullptr, nullptr, z0, nullptr, nullptr);

    // 5) LN1 (reduces z0+z1+bo) -> bf16 only (residual AND GEMM input)
    ln_kernel<<<M, 256, 0, stream>>>(z0, z1, nullptr, bo, ln1_g, ln1_b,
                                     nullptr, attnlnb);

    // 6) FFN up + relu + tanh-gelu -> bf16 (256-tile 2-phase)
    gemm256_kernel<2><<<dim3(F / 256, M / 256), 512, 131072, stream>>>(
        attnlnb, W1T, M, F, D, b1, hbuf);

    // 7) FFN down, split-K=2 (K=4096 -> 2x2048) -> bf16 partials z0,z1
    gemm128_kernel<4><<<dim3(D / 128, M / 128, 2), 256, 0, stream>>>(
        hbuf, W2T, M, D, F, F / 2, nullptr, nullptr, nullptr, z0, nullptr, nullptr);

    // 8) LN2 (reduces z0+z1+b2+bf16 resid) -> final output fp32
    ln_kernel<<<M, 256, 0, stream>>>(z0, z1, attnlnb, b2, ln2_g, ln2_b,
                                     out, nullptr);
}

// Round 16
// 239.148 us; speedup vs baseline: 1.7679x; 1.7679x over previous
//
#include <hip/hip_runtime.h>
#include <hip/hip_bf16.h>
#include <cstdint>
#include <cstddef>

typedef __attribute__((ext_vector_type(8))) short short8;   // 8 x bf16 (4 VGPRs)
typedef __attribute__((ext_vector_type(4))) float f32x4;    // MFMA accumulator
typedef __attribute__((ext_vector_type(4))) unsigned short ushort4v;

#define GLL(gp, lp) __builtin_amdgcn_global_load_lds(                         \
    (const __attribute__((address_space(1))) void*)(gp),                      \
    (__attribute__((address_space(3))) void*)(lp), 16, 0, 0)

static __device__ __forceinline__ unsigned short f2bf(float f) {
    union { float f; uint32_t u; } v; v.f = f;
    uint32_t r = v.u + 0x7FFF + ((v.u >> 16) & 1);   // round-to-nearest-even
    return (unsigned short)(r >> 16);
}
static __device__ __forceinline__ float bf2f(unsigned short u) {
    union { uint32_t u; float f; } v; v.u = (uint32_t)u << 16; return v.f;
}

// ---------------------------------------------------------------------------
// Fused preamble: weight transposes (KxN fp32 -> NxK bf16) + x fp32->bf16.
// ---------------------------------------------------------------------------
__global__ void pre_all_kernel(
    const float* __restrict__ x,
    const float* __restrict__ Wq, const float* __restrict__ Wk,
    const float* __restrict__ Wv, const float* __restrict__ Wo,
    const float* __restrict__ W1, const float* __restrict__ W2,
    unsigned short* __restrict__ xb,
    unsigned short* __restrict__ WqkvT, unsigned short* __restrict__ WoT,
    unsigned short* __restrict__ W1T, unsigned short* __restrict__ W2T)
{
    const int bid = blockIdx.x;
    const int tx = threadIdx.x, ty = threadIdx.y;      // block (32, 8)
    if (bid >= 12288) {                   // x conversion: 8 elems/thread
        const int tid = ty * 32 + tx;
        const size_t base = (size_t)(bid - 12288) * 2048 + tid * 8;
        float4 v0 = *reinterpret_cast<const float4*>(x + base);
        float4 v1 = *reinterpret_cast<const float4*>(x + base + 4);
        unsigned short* d = xb + base;
        d[0] = f2bf(v0.x); d[1] = f2bf(v0.y); d[2] = f2bf(v0.z); d[3] = f2bf(v0.w);
        d[4] = f2bf(v1.x); d[5] = f2bf(v1.y); d[6] = f2bf(v1.z); d[7] = f2bf(v1.w);
        return;
    }
    __shared__ float tile[32][33];
    const float* src; unsigned short* dst; int K, N, local;
    if (bid < 4096) {                     // Wq/Wk/Wv/Wo: 1024x1024
        int seg = bid >> 10; local = bid & 1023; K = 1024; N = 1024;
        src = (seg == 0) ? Wq : (seg == 1) ? Wk : (seg == 2) ? Wv : Wo;
        dst = (seg < 3) ? WqkvT + (size_t)seg * 1024 * 1024 : WoT;
    } else if (bid < 8192) {              // W1: 1024x4096
        local = bid - 4096; K = 1024; N = 4096; src = W1; dst = W1T;
    } else {                              // W2: 4096x1024
        local = bid - 8192; K = 4096; N = 1024; src = W2; dst = W2T;
    }
    const int ntx = N >> 5;
    const int n0 = (local % ntx) * 32, k0 = (local / ntx) * 32;
#pragma unroll
    for (int j = 0; j < 32; j += 8)
        tile[ty + j][tx] = src[(size_t)(k0 + ty + j) * N + n0 + tx];
    __syncthreads();
#pragma unroll
    for (int j = 0; j < 32; j += 8)
        dst[(size_t)(n0 + ty + j) * K + k0 + tx] = f2bf(tile[tx][ty + j]);
}

// ---------------------------------------------------------------------------
// 128x128 2-phase GEMM (R5/R9/R14-proven): BK=64, STAGE(next) issued first,
// ds_read + 32 MFMA on current, ONE vmcnt(0)+s_barrier per K-step.
// Split-K capable (grid.z, Kslice; ld = row stride).
// EPI: 0 = QKV split (+bias, Q*0.125*log2e, V transposed),
//      4 = bf16 partial to out0 + z*M*N
// ---------------------------------------------------------------------------
template <int EPI>
__global__ __launch_bounds__(256) void gemm128_kernel(
    const unsigned short* __restrict__ A, const unsigned short* __restrict__ BT,
    int M, int N, int ld, int Kslice,
    const float* __restrict__ bias0, const float* __restrict__ bias1,
    const float* __restrict__ bias2,
    void* __restrict__ out0, void* __restrict__ out1, void* __restrict__ out2)
{
    __shared__ unsigned short Asm[2][128 * 64];
    __shared__ unsigned short Bsm[2][128 * 64];

    const int t = threadIdx.x;
    const int lane = t & 63, wv = t >> 6;
    const int wr = wv >> 1, wc = wv & 1;

    const int gx = gridDim.x;
    const int nwg = gx * gridDim.y;
    const int id = blockIdx.y * gx + blockIdx.x;
    const int swz = (id & 7) * (nwg >> 3) + (id >> 3);
    const int rowBase = (swz / gx) * 128;
    const int colBase = (swz % gx) * 128;
    const int koff = blockIdx.z * Kslice;

    const int r0 = t >> 3, c0 = t & 7;
    const int cg = c0 ^ (r0 & 7);
    const unsigned short* gA = A + (size_t)(rowBase + r0) * ld + koff + cg * 8;
    const unsigned short* gB = BT + (size_t)(colBase + r0) * ld + koff + cg * 8;

    auto stage = [&](int buf, int kt) {
#pragma unroll
        for (int j = 0; j < 4; j++) {
            GLL(gA + (size_t)(32 * j) * ld + kt, &Asm[buf][t * 8 + 2048 * j]);
            GLL(gB + (size_t)(32 * j) * ld + kt, &Bsm[buf][t * 8 + 2048 * j]);
        }
    };

    int aoff[4][2], boff[4][2];
#pragma unroll
    for (int m = 0; m < 4; m++)
#pragma unroll
        for (int ks = 0; ks < 2; ks++) {
            int rl = wr * 64 + m * 16 + (lane & 15);
            aoff[m][ks] = rl * 64 + (((ks * 4 + (lane >> 4)) ^ (rl & 7)) << 3);
            int cl = wc * 64 + m * 16 + (lane & 15);
            boff[m][ks] = cl * 64 + (((ks * 4 + (lane >> 4)) ^ (cl & 7)) << 3);
        }

    f32x4 acc[4][4];
#pragma unroll
    for (int m = 0; m < 4; m++)
#pragma unroll
        for (int n = 0; n < 4; n++) acc[m][n] = (f32x4){0.f, 0.f, 0.f, 0.f};

    stage(0, 0);
    asm volatile("s_waitcnt vmcnt(0)" ::: "memory");
    __builtin_amdgcn_s_barrier();

    const int nt = Kslice >> 6;
    for (int tt = 0; tt < nt; ++tt) {
        const int cur = tt & 1;
        if (tt + 1 < nt) stage(cur ^ 1, (tt + 1) << 6);   // prefetch FIRST

        short8 b[4][2];
#pragma unroll
        for (int n = 0; n < 4; n++)
#pragma unroll
            for (int ks = 0; ks < 2; ks++)
                b[n][ks] = *(const short8*)&Bsm[cur][boff[n][ks]];
        __builtin_amdgcn_s_setprio(1);
#pragma unroll
        for (int m = 0; m < 4; m++) {
            short8 a0 = *(const short8*)&Asm[cur][aoff[m][0]];
            short8 a1 = *(const short8*)&Asm[cur][aoff[m][1]];
#pragma unroll
            for (int n = 0; n < 4; n++) {
                acc[m][n] = __builtin_amdgcn_mfma_f32_16x16x32_bf16(
                    a0, b[n][0], acc[m][n], 0, 0, 0);
                acc[m][n] = __builtin_amdgcn_mfma_f32_16x16x32_bf16(
                    a1, b[n][1], acc[m][n], 0, 0, 0);
            }
        }
        __builtin_amdgcn_s_setprio(0);

        asm volatile("s_waitcnt vmcnt(0)" ::: "memory");
        __builtin_amdgcn_sched_barrier(0);
        __builtin_amdgcn_s_barrier();
    }

#pragma unroll
    for (int m = 0; m < 4; m++) {
#pragma unroll
        for (int n = 0; n < 4; n++) {
            const int col = colBase + wc * 64 + n * 16 + (lane & 15);
#pragma unroll
            for (int i = 0; i < 4; i++) {
                const int row = rowBase + wr * 64 + m * 16 + (lane >> 4) * 4 + i;
                float v = acc[m][n][i];
                if (EPI == 0) {
                    const int bb = row >> 11, s = row & 2047;
                    if (col < 1024) {
                        float q = (v + bias0[col]) * 0.18033688011112042f;
                        int h = col >> 6, d = col & 63;
                        ((unsigned short*)out0)[((size_t)(bb * 16 + h) * 2048 + s) * 64 + d] = f2bf(q);
                    } else if (col < 2048) {
                        int cc = col - 1024;
                        float kv = v + bias1[cc];
                        int h = cc >> 6, d = cc & 63;
                        ((unsigned short*)out1)[((size_t)(bb * 16 + h) * 2048 + s) * 64 + d] = f2bf(kv);
                    } else {
                        int cc = col - 2048;
                        float vv = v + bias2[cc];
                        int h = cc >> 6, d = cc & 63;
                        ((unsigned short*)out2)[((size_t)(bb * 16 + h) * 64 + d) * 2048 + s] = f2bf(vv);
                    }
                } else {   // EPI == 4: bf16 partial
                    ((unsigned short*)out0)[(size_t)blockIdx.z * M * N + (size_t)row * N + col]
                        = f2bf(v);
                }
            }
        }
    }
}

// ---------------------------------------------------------------------------
// 256x256 2-phase GEMM (R9-proven for FFN-up): BK=64, 512 thr = 8 waves.
// EPI: 2 = bf16 tanh-gelu(relu(+bias))
// ---------------------------------------------------------------------------
template <int EPI>
__global__ __launch_bounds__(512, 2) void gemm256_kernel(
    const unsigned short* __restrict__ A, const unsigned short* __restrict__ BT,
    int M, int N, int K,
    const float* __restrict__ bias0, void* __restrict__ out0)
{
    extern __shared__ unsigned short lds[];   // 65536 elems = 128 KiB

    const int t = threadIdx.x, lane = t & 63, w = t >> 6;
    const int wm = w >> 2, wn = w & 3;

    const int gx = gridDim.x;
    const int nwg = gx * gridDim.y;
    const int id = blockIdx.y * gx + blockIdx.x;
    const int swz = (id & 7) * (nwg >> 3) + (id >> 3);
    const int rowBase = (swz / gx) * 256;
    const int colBase = (swz % gx) * 256;

    const int r0 = t >> 3, c0 = t & 7;
    const int cg = c0 ^ (r0 & 7);
    const unsigned short* gA = A + (size_t)(rowBase + r0) * K + cg * 8;
    const unsigned short* gB = BT + (size_t)(colBase + r0) * K + cg * 8;

    auto stage = [&](int buf, int kt) {
#pragma unroll
        for (int j = 0; j < 4; j++) {
            GLL(gA + (size_t)(64 * j) * K + kt, &lds[buf * 16384 + t * 8 + 4096 * j]);
            GLL(gB + (size_t)(64 * j) * K + kt, &lds[32768 + buf * 16384 + t * 8 + 4096 * j]);
        }
    };

    int aoff[8][2], boff[4][2];
#pragma unroll
    for (int mf = 0; mf < 8; mf++)
#pragma unroll
        for (int ks = 0; ks < 2; ks++) {
            int rl = wm * 128 + mf * 16 + (lane & 15);
            aoff[mf][ks] = rl * 64 + (((ks * 4 + (lane >> 4)) ^ (rl & 7)) << 3);
        }
#pragma unroll
    for (int nf = 0; nf < 4; nf++)
#pragma unroll
        for (int ks = 0; ks < 2; ks++) {
            int cl = wn * 64 + nf * 16 + (lane & 15);
            boff[nf][ks] = cl * 64 + (((ks * 4 + (lane >> 4)) ^ (cl & 7)) << 3);
        }

    f32x4 acc[8][4];
#pragma unroll
    for (int mf = 0; mf < 8; mf++)
#pragma unroll
        for (int nf = 0; nf < 4; nf++) acc[mf][nf] = (f32x4){0.f, 0.f, 0.f, 0.f};

    stage(0, 0);
    asm volatile("s_waitcnt vmcnt(0)" ::: "memory");
    __builtin_amdgcn_s_barrier();

    const int nt = K >> 6;
    for (int tt = 0; tt < nt; ++tt) {
        const int cur = tt & 1;
        const int ab = cur * 16384, bbase = 32768 + cur * 16384;
        if (tt + 1 < nt) stage(cur ^ 1, (tt + 1) << 6);

        short8 b[4][2];
#pragma unroll
        for (int nf = 0; nf < 4; nf++)
#pragma unroll
            for (int ks = 0; ks < 2; ks++)
                b[nf][ks] = *(const short8*)&lds[bbase + boff[nf][ks]];
        __builtin_amdgcn_s_setprio(1);
#pragma unroll
        for (int mf = 0; mf < 8; mf++) {
            short8 a0 = *(const short8*)&lds[ab + aoff[mf][0]];
            short8 a1 = *(const short8*)&lds[ab + aoff[mf][1]];
#pragma unroll
            for (int nf = 0; nf < 4; nf++) {
                acc[mf][nf] = __builtin_amdgcn_mfma_f32_16x16x32_bf16(
                    a0, b[nf][0], acc[mf][nf], 0, 0, 0);
                acc[mf][nf] = __builtin_amdgcn_mfma_f32_16x16x32_bf16(
                    a1, b[nf][1], acc[mf][nf], 0, 0, 0);
            }
        }
        __builtin_amdgcn_s_setprio(0);

        asm volatile("s_waitcnt vmcnt(0)" ::: "memory");
        __builtin_amdgcn_sched_barrier(0);
        __builtin_amdgcn_s_barrier();
    }

#pragma unroll
    for (int mf = 0; mf < 8; mf++) {
#pragma unroll
        for (int nf = 0; nf < 4; nf++) {
            const int col = colBase + wn * 64 + nf * 16 + (lane & 15);
#pragma unroll
            for (int i = 0; i < 4; i++) {
                const int row = rowBase + wm * 128 + mf * 16 + (lane >> 4) * 4 + i;
                float z = acc[mf][nf][i] + bias0[col];
                if (z > 0.f) {
                    float u = 0.7978845608f * (z + 0.044715f * z * z * z);
                    float e = __builtin_amdgcn_exp2f(u * 2.8853900817779268f);
                    z = z * (1.f - 1.f / (e + 1.f));
                } else z = 0.f;
                ((unsigned short*)out0)[(size_t)row * N + col] = f2bf(z);
            }
        }
    }
}

// ---------------------------------------------------------------------------
// Flash attention (R14-proven): 512 threads = 8 waves x 16 q-rows.
// Grid (S/128, B*H); LDS 48 KB; 2-phase dbuf K/V; shift-free exp2 softmax;
// l via ones-MFMA.
// ---------------------------------------------------------------------------
__global__ __launch_bounds__(512) void flash_attn_kernel(
    const unsigned short* __restrict__ Qb, const unsigned short* __restrict__ Kb,
    const unsigned short* __restrict__ VT, unsigned short* __restrict__ ctxb)
{
    __shared__ unsigned short Ksm[2][64 * 64];
    __shared__ unsigned short Vsm[2][64 * 64];
    __shared__ unsigned short Psm[8][16 * 64];

    const int bh = blockIdx.y;
    const int q0 = blockIdx.x * 128;
    const int t = threadIdx.x, lane = t & 63, wv = t >> 6;

    const unsigned short* Qg = Qb + (size_t)bh * 2048 * 64;
    const unsigned short* Kg = Kb + (size_t)bh * 2048 * 64;
    const unsigned short* Vg = VT + (size_t)bh * 64 * 2048;

    short8 qf[2];
    {
        int r = q0 + wv * 16 + (lane & 15);
        qf[0] = *(const short8*)&Qg[(size_t)r * 64 + ((lane >> 4) << 3)];
        qf[1] = *(const short8*)&Qg[(size_t)r * 64 + 32 + ((lane >> 4) << 3)];
    }

    short8 onesf;
#pragma unroll
    for (int j = 0; j < 8; j++) onesf[j] = (short)0x3F80;   // bf16 1.0

    f32x4 o[4], lacc;
#pragma unroll
    for (int n = 0; n < 4; n++) o[n] = (f32x4){0.f, 0.f, 0.f, 0.f};
    lacc = (f32x4){0.f, 0.f, 0.f, 0.f};

    const int r0 = t >> 3, sl = t & 7;
    const int cg0 = sl ^ (r0 & 7);

    auto stageKV = [&](int buf, int kt) {
        GLL(&Kg[(size_t)(kt + r0) * 64 + cg0 * 8], &Ksm[buf][t * 8]);
        GLL(&Vg[(size_t)r0 * 2048 + kt + cg0 * 8], &Vsm[buf][t * 8]);
    };

    unsigned short* P = &Psm[wv][0];

    int pwaddr[4][4];
#pragma unroll
    for (int n = 0; n < 4; n++)
#pragma unroll
        for (int i = 0; i < 4; i++) {
            int rl = (lane >> 4) * 4 + i;
            int col = n * 16 + (lane & 15);
            pwaddr[n][i] = rl * 64 + ((((col >> 3) ^ (rl & 7)) << 3) | (col & 7));
        }

    stageKV(0, 0);
    asm volatile("s_waitcnt vmcnt(0)" ::: "memory");
    __builtin_amdgcn_s_barrier();

    for (int tt = 0; tt < 32; ++tt) {
        const int cur = tt & 1;
        if (tt + 1 < 32) stageKV(cur ^ 1, (tt + 1) << 6);   // prefetch FIRST

        f32x4 s[4];
        __builtin_amdgcn_s_setprio(1);
#pragma unroll
        for (int n = 0; n < 4; n++) {
            s[n] = (f32x4){0.f, 0.f, 0.f, 0.f};
            int rl = n * 16 + (lane & 15);
#pragma unroll
            for (int kb = 0; kb < 2; kb++) {
                int slot = ((kb << 2) + (lane >> 4)) ^ (rl & 7);
                short8 kf = *(const short8*)&Ksm[cur][rl * 64 + slot * 8];
                s[n] = __builtin_amdgcn_mfma_f32_16x16x32_bf16(qf[kb], kf, s[n], 0, 0, 0);
            }
        }
        __builtin_amdgcn_s_setprio(0);

#pragma unroll
        for (int n = 0; n < 4; n++)
#pragma unroll
            for (int i = 0; i < 4; i++) {
                float p = __builtin_amdgcn_exp2f(s[n][i]);
                union { float f; uint32_t u; } pv; pv.f = p;
                P[pwaddr[n][i]] = (unsigned short)(pv.u >> 16);
            }

        short8 pf[2];
        {
            int rl = lane & 15;
#pragma unroll
            for (int kb = 0; kb < 2; kb++) {
                int slot = ((kb << 2) + (lane >> 4)) ^ (rl & 7);
                pf[kb] = *(const short8*)&P[rl * 64 + slot * 8];
            }
        }
        __builtin_amdgcn_s_setprio(1);
        lacc = __builtin_amdgcn_mfma_f32_16x16x32_bf16(pf[0], onesf, lacc, 0, 0, 0);
        lacc = __builtin_amdgcn_mfma_f32_16x16x32_bf16(pf[1], onesf, lacc, 0, 0, 0);
#pragma unroll
        for (int n = 0; n < 4; n++) {
            int d = n * 16 + (lane & 15);
#pragma unroll
            for (int kb = 0; kb < 2; kb++) {
                int slot = ((kb << 2) + (lane >> 4)) ^ (d & 7);
                short8 vf = *(const short8*)&Vsm[cur][d * 64 + slot * 8];
                o[n] = __builtin_amdgcn_mfma_f32_16x16x32_bf16(pf[kb], vf, o[n], 0, 0, 0);
            }
        }
        __builtin_amdgcn_s_setprio(0);

        asm volatile("s_waitcnt vmcnt(0)" ::: "memory");
        __builtin_amdgcn_sched_barrier(0);
        __builtin_amdgcn_s_barrier();
    }

    const int bb = bh >> 4, h = bh & 15;
#pragma unroll
    for (int i = 0; i < 4; i++) {
        float linv = 1.f / lacc[i];
        int srow = q0 + wv * 16 + (lane >> 4) * 4 + i;
#pragma unroll
        for (int n = 0; n < 4; n++) {
            int d = n * 16 + (lane & 15);
            ctxb[((size_t)(bb * 2048 + srow)) * 1024 + h * 64 + d] =
                f2bf(o[n][i] * linv);
        }
    }
}

// ---------------------------------------------------------------------------
// LayerNorm over D=1024 with fused split-K reduce; bf16 partial inputs.
// ---------------------------------------------------------------------------
__global__ __launch_bounds__(256) void ln_kernel(
    const unsigned short* __restrict__ in0, const unsigned short* __restrict__ in1,
    const unsigned short* __restrict__ resid, const float* __restrict__ bias,
    const float* __restrict__ g, const float* __restrict__ bta,
    float* __restrict__ outf, unsigned short* __restrict__ outb)
{
    const int row = blockIdx.x;
    const int t = threadIdx.x, lane = t & 63, wv = t >> 6;
    const size_t base = (size_t)row * 1024 + t * 4;

    ushort4v u0 = *reinterpret_cast<const ushort4v*>(in0 + base);
    ushort4v u1 = *reinterpret_cast<const ushort4v*>(in1 + base);
    float4 xv;
    xv.x = bf2f(u0[0]) + bf2f(u1[0]);
    xv.y = bf2f(u0[1]) + bf2f(u1[1]);
    xv.z = bf2f(u0[2]) + bf2f(u1[2]);
    xv.w = bf2f(u0[3]) + bf2f(u1[3]);
    if (resid) {
        ushort4v ur = *reinterpret_cast<const ushort4v*>(resid + base);
        xv.x += bf2f(ur[0]); xv.y += bf2f(ur[1]);
        xv.z += bf2f(ur[2]); xv.w += bf2f(ur[3]);
    }
    {
        float4 bv = *reinterpret_cast<const float4*>(bias + t * 4);
        xv.x += bv.x; xv.y += bv.y; xv.z += bv.z; xv.w += bv.w;
    }

    float s = xv.x + xv.y + xv.z + xv.w;
    float ss = xv.x * xv.x + xv.y * xv.y + xv.z * xv.z + xv.w * xv.w;
#pragma unroll
    for (int off = 1; off < 64; off <<= 1) {
        s += __shfl_xor(s, off);
        ss += __shfl_xor(ss, off);
    }
    __shared__ float red[8];
    if (lane == 0) { red[wv] = s; red[4 + wv] = ss; }
    __syncthreads();
    s = red[0] + red[1] + red[2] + red[3];
    ss = red[4] + red[5] + red[6] + red[7];
    const float mu = s * (1.f / 1024.f);
    const float var = ss * (1.f / 1024.f) - mu * mu;
    const float inv = rsqrtf(var + 1e-12f);

    float4 gv = *reinterpret_cast<const float4*>(g + t * 4);
    float4 bv = *reinterpret_cast<const float4*>(bta + t * 4);
    float o0 = (xv.x - mu) * inv * gv.x + bv.x;
    float o1 = (xv.y - mu) * inv * gv.y + bv.y;
    float o2 = (xv.z - mu) * inv * gv.z + bv.z;
    float o3 = (xv.w - mu) * inv * gv.w + bv.w;

    if (outf)
        *reinterpret_cast<float4*>(outf + base) = (float4){o0, o1, o2, o3};
    if (outb) {
        unsigned short* ob = outb + base;
        ob[0] = f2bf(o0); ob[1] = f2bf(o1); ob[2] = f2bf(o2); ob[3] = f2bf(o3);
    }
}

// ---------------------------------------------------------------------------
extern "C" void kernel_launch(void* const* d_in, const int* in_sizes, int n_in,
                              void* d_out, int out_size, void* d_ws, size_t ws_size,
                              hipStream_t stream) {
    const float* x     = (const float*)d_in[0];
    const float* Wq    = (const float*)d_in[1];
    const float* bq    = (const float*)d_in[2];
    const float* Wk    = (const float*)d_in[3];
    const float* bk    = (const float*)d_in[4];
    const float* Wv    = (const float*)d_in[5];
    const float* bv    = (const float*)d_in[6];
    const float* Wo    = (const float*)d_in[7];
    const float* bo    = (const float*)d_in[8];
    const float* ln1_g = (const float*)d_in[9];
    const float* ln1_b = (const float*)d_in[10];
    const float* W1    = (const float*)d_in[11];
    const float* b1    = (const float*)d_in[12];
    const float* W2    = (const float*)d_in[13];
    const float* b2    = (const float*)d_in[14];
    const float* ln2_g = (const float*)d_in[15];
    const float* ln2_b = (const float*)d_in[16];
    float* out = (float*)d_out;

    const int B = 2, S = 2048, D = 1024, H = 16, F = 4096;
    const int M = B * S;                    // 4096 tokens

    char* w = (char*)d_ws;
    size_t off = 0;
    auto alloc = [&](size_t bytes) {
        size_t o = off; off += (bytes + 255) & ~(size_t)255; return o;
    };
    unsigned short* xb      = (unsigned short*)(w + alloc((size_t)M * D * 2));   // also ctxb
    unsigned short* WqkvT   = (unsigned short*)(w + alloc((size_t)3 * D * D * 2));
    unsigned short* WoT     = (unsigned short*)(w + alloc((size_t)D * D * 2));
    unsigned short* W1T     = (unsigned short*)(w + alloc((size_t)D * F * 2));
    unsigned short* W2T     = (unsigned short*)(w + alloc((size_t)F * D * 2));
    unsigned short* Qbuf    = (unsigned short*)(w + alloc((size_t)M * D * 2));
    unsigned short* Kbuf    = (unsigned short*)(w + alloc((size_t)M * D * 2));
    unsigned short* VTbuf   = (unsigned short*)(w + alloc((size_t)M * D * 2));
    unsigned short* z0      = (unsigned short*)(w + alloc((size_t)M * D * 2));   // bf16 partial 0
    unsigned short* z1      = (unsigned short*)(w + alloc((size_t)M * D * 2));   // bf16 partial 1
    unsigned short* attnlnb = (unsigned short*)(w + alloc((size_t)M * D * 2));   // LN1 out (bf16)
    unsigned short* hbuf    = (unsigned short*)(w + alloc((size_t)M * F * 2));
    unsigned short* ctxb    = xb;   // reuse (xb consumed by QKV GEMM before attn)

    hipFuncSetAttribute((const void*)gemm256_kernel<2>,
                        hipFuncAttributeMaxDynamicSharedMemorySize, 131072);

    // 1) fused preamble: weight transposes + x conversion (one launch)
    pre_all_kernel<<<14336, dim3(32, 8), 0, stream>>>(
        x, Wq, Wk, Wv, Wo, W1, W2, xb, WqkvT, WoT, W1T, W2T);

    // 2) fused QKV projection (128-tile 2-phase, grid 768)
    gemm128_kernel<0><<<dim3(3 * D / 128, M / 128, 1), 256, 0, stream>>>(
        xb, WqkvT, M, 3 * D, D, D, bq, bk, bv, Qbuf, Kbuf, VTbuf);

    // 3) flash attention -> ctx bf16 (token-major); 128 q-rows/block
    flash_attn_kernel<<<dim3(S / 128, B * H), 512, 0, stream>>>(
        Qbuf, Kbuf, VTbuf, ctxb);

    // 4) output projection, split-K=2 -> bf16 partials z0,z1
    gemm128_kernel<4><<<dim3(D / 128, M / 128, 2), 256, 0, stream>>>(
        ctxb, WoT, M, D, D, D / 2, nullptr, nullptr, nullptr, z0, nullptr, nullptr);

    // 5) LN1 (reduces z0+z1+bo) -> bf16 only (residual AND GEMM input)
    ln_kernel<<<M, 256, 0, stream>>>(z0, z1, nullptr, bo, ln1_g, ln1_b,
                                     nullptr, attnlnb);

    // 6) FFN up + relu + tanh-gelu -> bf16 (256-tile 2-phase)
    gemm256_kernel<2><<<dim3(F / 256, M / 256), 512, 131072, stream>>>(
        attnlnb, W1T, M, F, D, b1, hbuf);

    // 7) FFN down, split-K=2 (K=4096 -> 2x2048) -> bf16 partials z0,z1
    gemm128_kernel<4><<<dim3(D / 128, M / 128, 2), 256, 0, stream>>>(
        hbuf, W2T, M, D, F, F / 2, nullptr, nullptr, nullptr, z0, nullptr, nullptr);

    // 8) LN2 (reduces z0+z1+b2+bf16 resid) -> final output fp32
    ln_kernel<<<M, 256, 0, stream>>>(z0, z1, attnlnb, b2, ln2_g, ln2_b,
                                     out, nullptr);
}